// Round 6
// baseline (113.402 us; speedup 1.0000x reference)
//
#include <hip/hip_runtime.h>

#define NN   4096
#define MM   8191   // 2*NN - 1
#define BB   256
#define CAP  256    // u16 slots per row (nnz/row ~41, max ~70)
#define REPS 2      // diagnostic: compact covers the row-space twice

__device__ __forceinline__ int prefix_lt(unsigned long long m) {
    return __builtin_amdgcn_mbcnt_hi((unsigned)(m >> 32),
           __builtin_amdgcn_mbcnt_lo((unsigned)m, 0u));
}

// ---------------------------------------------------------------------------
// k_prep: zero w1sum[256]; dd = d1 - d2 (f32, float4). Grid 1024 = exactly one
// element per thread.
// ---------------------------------------------------------------------------
__global__ __launch_bounds__(256) void k_prep(const float4* __restrict__ d1,
                                              const float4* __restrict__ d2,
                                              float* __restrict__ w1sum,
                                              float4* __restrict__ dd4,
                                              int make_dd) {
    int idx = blockIdx.x * 256 + threadIdx.x;
    if (idx < BB) w1sum[idx] = 0.0f;
    if (make_dd) {
        float4 a = d1[idx], b = d2[idx];
        float4 r; r.x = a.x - b.x; r.y = a.y - b.y;
        r.z = a.z - b.z; r.w = a.w - b.w;
        dd4[idx] = r;
    }
}

// ---------------------------------------------------------------------------
// k_compact: one wave per ROW (8192 waves >= 8191 rows). Two sequential
// 8-load halves per row; ballot+mbcnt compaction into a per-wave u16 LDS
// buffer; direct cnt[m] store (no atomics -> idempotent); uint4 writeout.
// REPS=2 covers the row space twice for timing decomposition.
// ---------------------------------------------------------------------------
__global__ __launch_bounds__(256, 4) void k_compact(
        const float4* __restrict__ st4,
        int* __restrict__ cnt,
        unsigned short* __restrict__ list) {
    __shared__ unsigned short s_buf[4][CAP];
    const int wave = threadIdx.x >> 6;
    const int lane = threadIdx.x & 63;
    unsigned short* buf = s_buf[wave];
    const int m = blockIdx.x * 4 + wave;

    for (int rep = 0; rep < REPS; ++rep) {
        if (m >= MM) continue;
        int c = 0;
        #pragma unroll
        for (int h = 0; h < 2; ++h) {
            const float4* base = st4 + (size_t)m * (NN / 4) + h * (NN / 8);
            float4 v0 = base[lane];
            float4 v1 = base[64  + lane];
            float4 v2 = base[128 + lane];
            float4 v3 = base[192 + lane];
            float4 v4 = base[256 + lane];
            float4 v5 = base[320 + lane];
            float4 v6 = base[384 + lane];
            float4 v7 = base[448 + lane];

            const int cb = h * (NN / 2);
            #define SITE(val, col)                                          \
            {                                                               \
                unsigned long long mk = __ballot((val) != 0.0f);            \
                if ((val) != 0.0f)                                          \
                    buf[c + prefix_lt(mk)] = (unsigned short)(col);         \
                c += __popcll(mk);                                          \
            }
            #define QUAD(v, cb0)                                            \
                SITE(v.x, (cb0))     SITE(v.y, (cb0) + 1)                   \
                SITE(v.z, (cb0) + 2) SITE(v.w, (cb0) + 3)
            QUAD(v0, cb + (lane)       * 4)
            QUAD(v1, cb + (64  + lane) * 4)
            QUAD(v2, cb + (128 + lane) * 4)
            QUAD(v3, cb + (192 + lane) * 4)
            QUAD(v4, cb + (256 + lane) * 4)
            QUAD(v5, cb + (320 + lane) * 4)
            QUAD(v6, cb + (384 + lane) * 4)
            QUAD(v7, cb + (448 + lane) * 4)
            #undef QUAD
            #undef SITE
        }
        __builtin_amdgcn_wave_barrier();   // LDS writes before reads

        if (lane == 0) cnt[m] = c;
        uint4* lv = (uint4*)(list + (size_t)m * CAP);
        const int nv = (c + 7) >> 3;       // uint4 chunks holding 8 u16 each
        if (lane < nv) lv[lane] = ((const uint4*)buf)[lane];
        __builtin_amdgcn_wave_barrier();   // reads before next rep's writes
    }
}

// ---------------------------------------------------------------------------
// k_gather: one wave per row. List preloaded to LDS (8B/lane, one load);
// 4-deep float4 gathers from the 4 MB f32 dd (L2-resident) into 2 accums.
// Block LDS reduction, one global atomic per thread.
// ---------------------------------------------------------------------------
__global__ __launch_bounds__(256, 8) void k_gather(
        const float4* __restrict__ d1,
        const float4* __restrict__ d2,
        const float4* __restrict__ dd4,
        int use_dd,
        const int* __restrict__ cnt,
        const unsigned short* __restrict__ list,
        const float* __restrict__ param,
        const int*   __restrict__ parents,
        float* __restrict__ w1sum) {
    __shared__ unsigned long long s_listq[4][CAP / 4];   // 64 qwords/wave
    __shared__ float s_part[BB];
    const int tid  = threadIdx.x;
    const int wave = tid >> 6;
    const int lane = tid & 63;

    s_part[tid] = 0.0f;
    __syncthreads();

    const int m = blockIdx.x * 4 + wave;
    float4 a0 = {0, 0, 0, 0}, a1 = {0, 0, 0, 0};
    float wgt = 0.0f;

    if (m < MM) {
        int c = cnt[m];
        if (c > CAP) c = CAP;
        const unsigned long long* lsrc =
            (const unsigned long long*)(list + (size_t)m * CAP);
        s_listq[wave][lane] = lsrc[lane];
        __builtin_amdgcn_wave_barrier();

        int i = 0;
        if (use_dd) {
            for (; i + 4 <= c; i += 4) {
                unsigned long long pk = s_listq[wave][i >> 2];
                int n0 = (int)( pk        & 0xffffULL);
                int n1 = (int)((pk >> 16) & 0xffffULL);
                int n2 = (int)((pk >> 32) & 0xffffULL);
                int n3 = (int)((pk >> 48) & 0xffffULL);
                float4 g0 = dd4[(size_t)n0 * 64 + lane];
                float4 g1 = dd4[(size_t)n1 * 64 + lane];
                float4 g2 = dd4[(size_t)n2 * 64 + lane];
                float4 g3 = dd4[(size_t)n3 * 64 + lane];
                a0.x += g0.x; a0.y += g0.y; a0.z += g0.z; a0.w += g0.w;
                a1.x += g1.x; a1.y += g1.y; a1.z += g1.z; a1.w += g1.w;
                a0.x += g2.x; a0.y += g2.y; a0.z += g2.z; a0.w += g2.w;
                a1.x += g3.x; a1.y += g3.y; a1.z += g3.z; a1.w += g3.w;
            }
            for (; i < c; ++i) {
                int n = (int)((s_listq[wave][i >> 2] >> ((i & 3) * 16)) & 0xffffULL);
                float4 g = dd4[(size_t)n * 64 + lane];
                a0.x += g.x; a0.y += g.y; a0.z += g.z; a0.w += g.w;
            }
        } else {
            for (; i < c; ++i) {
                int n = (int)((s_listq[wave][i >> 2] >> ((i & 3) * 16)) & 0xffffULL);
                float4 u = d1[(size_t)n * 64 + lane];
                float4 w = d2[(size_t)n * 64 + lane];
                a0.x += u.x - w.x; a0.y += u.y - w.y;
                a0.z += u.z - w.z; a0.w += u.w - w.w;
            }
        }
        wgt = param[parents[m]] - param[m];
    }

    atomicAdd(&s_part[4 * lane + 0], wgt * fabsf(a0.x + a1.x));
    atomicAdd(&s_part[4 * lane + 1], wgt * fabsf(a0.y + a1.y));
    atomicAdd(&s_part[4 * lane + 2], wgt * fabsf(a0.z + a1.z));
    atomicAdd(&s_part[4 * lane + 3], wgt * fabsf(a0.w + a1.w));
    __syncthreads();
    atomicAdd(&w1sum[tid], s_part[tid]);
}

// ---------------------------------------------------------------------------
// k_finalize: out = sum_b (ot[b] - 0.5 * w1sum[b])^2
// ---------------------------------------------------------------------------
__global__ __launch_bounds__(256) void k_finalize(const float* __restrict__ w1sum,
                                                  const float* __restrict__ ot,
                                                  float* __restrict__ out) {
    __shared__ float s[4];
    int tid = threadIdx.x;
    float e = ot[tid] - 0.5f * w1sum[tid];
    float v = e * e;
    #pragma unroll
    for (int off = 32; off > 0; off >>= 1) v += __shfl_down(v, off, 64);
    if ((tid & 63) == 0) s[tid >> 6] = v;
    __syncthreads();
    if (tid == 0) out[0] = (s[0] + s[1]) + (s[2] + s[3]);
}

// ---------------------------------------------------------------------------
extern "C" void kernel_launch(void* const* d_in, const int* in_sizes, int n_in,
                              void* d_out, int out_size, void* d_ws, size_t ws_size,
                              hipStream_t stream) {
    const float* d1      = (const float*)d_in[0];
    const float* d2      = (const float*)d_in[1];
    const float* ot      = (const float*)d_in[2];
    const float* subtree = (const float*)d_in[3];
    const float* param   = (const float*)d_in[4];
    const int*   parents = (const int*)d_in[5];

    char* wsb = (char*)d_ws;
    float* w1sum = (float*)wsb;                       // 256 f
    int*   cnt   = (int*)(wsb + 1024);                // MM ints
    size_t off = 1024 + (size_t)MM * 4;
    off = (off + 15) & ~(size_t)15;                   // 33792

    const size_t listbytes = (size_t)MM * CAP * 2;    // ~4.2 MB
    const size_t ddbytes   = (size_t)NN * BB * 4;     // 4 MB f32

    unsigned short* list = (unsigned short*)(wsb + off);
    size_t ddoff = off + listbytes;
    ddoff = (ddoff + 15) & ~(size_t)15;

    float4* dd4 = nullptr;
    int use_dd = 0;
    if (ws_size >= ddoff + ddbytes) {
        use_dd = 1;
        dd4 = (float4*)(wsb + ddoff);
    }

    k_prep<<<1024, 256, 0, stream>>>((const float4*)d1, (const float4*)d2,
                                     w1sum, dd4, use_dd);
    k_compact<<<2048, 256, 0, stream>>>((const float4*)subtree, cnt, list);
    k_gather<<<2048, 256, 0, stream>>>((const float4*)d1, (const float4*)d2,
                                       dd4, use_dd, cnt, list,
                                       param, parents, w1sum);
    k_finalize<<<1, 256, 0, stream>>>(w1sum, ot, (float*)d_out);
}